// Round 1
// baseline (203.679 us; speedup 1.0000x reference)
//
#include <hip/hip_runtime.h>

// TrajLoss: sum over i of (x[i]-pred[i])^2 + (y[i]-pred[i+1])^2
// N = 16,777,216; pred has N+1 elements. Memory-bound streaming reduction.

__global__ void TrajLoss_zero_kernel(float* out) {
    if (threadIdx.x == 0 && blockIdx.x == 0) out[0] = 0.0f;
}

__global__ __launch_bounds__(256) void TrajLoss_6141803233879_kernel(
    const float* __restrict__ pred,
    const float* __restrict__ x,
    const float* __restrict__ y,
    float* __restrict__ out,
    int n4,   // n / 4 (float4 count)
    int n)    // total elements
{
    const int tid    = blockIdx.x * blockDim.x + threadIdx.x;
    const int stride = gridDim.x * blockDim.x;

    float acc = 0.0f;
    const float4* x4 = (const float4*)x;
    const float4* y4 = (const float4*)y;
    const float4* p4v = (const float4*)pred;

    for (int i = tid; i < n4; i += stride) {
        const int base = i << 2;
        float4 xv = x4[i];
        float4 yv = y4[i];
        float4 p0 = p4v[i];
        float  p4 = pred[base + 4];   // next line; L1/L2 hit (neighbor lane's float4)

        float dx0 = xv.x - p0.x;
        float dx1 = xv.y - p0.y;
        float dx2 = xv.z - p0.z;
        float dx3 = xv.w - p0.w;
        float dy0 = yv.x - p0.y;
        float dy1 = yv.y - p0.z;
        float dy2 = yv.z - p0.w;
        float dy3 = yv.w - p4;

        acc += dx0*dx0 + dy0*dy0;
        acc += dx1*dx1 + dy1*dy1;
        acc += dx2*dx2 + dy2*dy2;
        acc += dx3*dx3 + dy3*dy3;
    }

    // Tail (n not divisible by 4) — handled by thread 0 only; N is divisible
    // by 4 here so this is dead code in practice.
    if (tid == 0) {
        for (int i = n4 << 2; i < n; ++i) {
            float dx = x[i] - pred[i];
            float dy = y[i] - pred[i + 1];
            acc += dx * dx + dy * dy;
        }
    }

    // Wave-64 butterfly reduce
    #pragma unroll
    for (int off = 32; off > 0; off >>= 1)
        acc += __shfl_down(acc, off, 64);

    __shared__ float smem[4];   // 256 threads = 4 waves
    const int lane = threadIdx.x & 63;
    const int wave = threadIdx.x >> 6;
    if (lane == 0) smem[wave] = acc;
    __syncthreads();

    if (threadIdx.x == 0) {
        float s = smem[0] + smem[1] + smem[2] + smem[3];
        atomicAdd(out, s);   // device-scope by default on gfx950
    }
}

extern "C" void kernel_launch(void* const* d_in, const int* in_sizes, int n_in,
                              void* d_out, int out_size, void* d_ws, size_t ws_size,
                              hipStream_t stream) {
    const float* pred = (const float*)d_in[0];   // N+1 floats
    const float* x    = (const float*)d_in[1];   // N floats
    const float* y    = (const float*)d_in[2];   // N floats
    float* out = (float*)d_out;

    const int n  = in_sizes[1];
    const int n4 = n >> 2;

    TrajLoss_zero_kernel<<<1, 64, 0, stream>>>(out);

    const int block = 256;
    // 4096 blocks * 256 threads * float4 = 4,194,304 elems/pass -> 4 passes at N=16.7M
    const int grid = 4096;
    TrajLoss_6141803233879_kernel<<<grid, block, 0, stream>>>(pred, x, y, out, n4, n);
}

// Round 2
// 198.896 us; speedup vs baseline: 1.0240x; 1.0240x over previous
//
#include <hip/hip_runtime.h>

// TrajLoss: sum over i of (x[i]-pred[i])^2 + (y[i]-pred[i+1])^2
// N = 16,777,216; pred has N+1 elements. Memory-bound streaming reduction.
//
// R1: 4x manual unroll of the grid-stride loop. R0 had VGPR_Count=16 ->
// only one iteration's loads in flight -> latency-bound at 2.5 TB/s logical.
// Issuing 12 dwordx4 + 4 dword loads before any use quadruples MLP.

__global__ void TrajLoss_zero_kernel(float* out) {
    if (threadIdx.x == 0 && blockIdx.x == 0) out[0] = 0.0f;
}

__global__ __launch_bounds__(256) void TrajLoss_6141803233879_kernel(
    const float* __restrict__ pred,
    const float* __restrict__ x,
    const float* __restrict__ y,
    float* __restrict__ out,
    int n4,   // n / 4 (float4 count)
    int n)    // total elements
{
    const int tid    = blockIdx.x * blockDim.x + threadIdx.x;
    const int stride = gridDim.x * blockDim.x;

    float acc = 0.0f;
    const float4* x4 = (const float4*)x;
    const float4* y4 = (const float4*)y;
    const float4* p4v = (const float4*)pred;

    int i = tid;

    // Main path: 4 independent float4 iterations, all loads issued up front.
    for (; i + 3 * stride < n4; i += 4 * stride) {
        const int i0 = i;
        const int i1 = i + stride;
        const int i2 = i + 2 * stride;
        const int i3 = i + 3 * stride;

        float4 xv0 = x4[i0], xv1 = x4[i1], xv2 = x4[i2], xv3 = x4[i3];
        float4 yv0 = y4[i0], yv1 = y4[i1], yv2 = y4[i2], yv3 = y4[i3];
        float4 p0  = p4v[i0], p1 = p4v[i1], p2 = p4v[i2], p3 = p4v[i3];
        float  q0 = pred[(i0 << 2) + 4];
        float  q1 = pred[(i1 << 2) + 4];
        float  q2 = pred[(i2 << 2) + 4];
        float  q3 = pred[(i3 << 2) + 4];

        float dx, dy;
        dx = xv0.x - p0.x; dy = yv0.x - p0.y; acc += dx*dx + dy*dy;
        dx = xv0.y - p0.y; dy = yv0.y - p0.z; acc += dx*dx + dy*dy;
        dx = xv0.z - p0.z; dy = yv0.z - p0.w; acc += dx*dx + dy*dy;
        dx = xv0.w - p0.w; dy = yv0.w - q0;   acc += dx*dx + dy*dy;

        dx = xv1.x - p1.x; dy = yv1.x - p1.y; acc += dx*dx + dy*dy;
        dx = xv1.y - p1.y; dy = yv1.y - p1.z; acc += dx*dx + dy*dy;
        dx = xv1.z - p1.z; dy = yv1.z - p1.w; acc += dx*dx + dy*dy;
        dx = xv1.w - p1.w; dy = yv1.w - q1;   acc += dx*dx + dy*dy;

        dx = xv2.x - p2.x; dy = yv2.x - p2.y; acc += dx*dx + dy*dy;
        dx = xv2.y - p2.y; dy = yv2.y - p2.z; acc += dx*dx + dy*dy;
        dx = xv2.z - p2.z; dy = yv2.z - p2.w; acc += dx*dx + dy*dy;
        dx = xv2.w - p2.w; dy = yv2.w - q2;   acc += dx*dx + dy*dy;

        dx = xv3.x - p3.x; dy = yv3.x - p3.y; acc += dx*dx + dy*dy;
        dx = xv3.y - p3.y; dy = yv3.y - p3.z; acc += dx*dx + dy*dy;
        dx = xv3.z - p3.z; dy = yv3.z - p3.w; acc += dx*dx + dy*dy;
        dx = xv3.w - p3.w; dy = yv3.w - q3;   acc += dx*dx + dy*dy;
    }

    // Remainder float4 iterations.
    for (; i < n4; i += stride) {
        float4 xv = x4[i];
        float4 yv = y4[i];
        float4 p0 = p4v[i];
        float  q  = pred[(i << 2) + 4];
        float dx, dy;
        dx = xv.x - p0.x; dy = yv.x - p0.y; acc += dx*dx + dy*dy;
        dx = xv.y - p0.y; dy = yv.y - p0.z; acc += dx*dx + dy*dy;
        dx = xv.z - p0.z; dy = yv.z - p0.w; acc += dx*dx + dy*dy;
        dx = xv.w - p0.w; dy = yv.w - q;    acc += dx*dx + dy*dy;
    }

    // Scalar tail (n not divisible by 4) — dead code for N=16.7M.
    if (tid == 0) {
        for (int j = n4 << 2; j < n; ++j) {
            float dx = x[j] - pred[j];
            float dy = y[j] - pred[j + 1];
            acc += dx * dx + dy * dy;
        }
    }

    // Wave-64 reduce
    #pragma unroll
    for (int off = 32; off > 0; off >>= 1)
        acc += __shfl_down(acc, off, 64);

    __shared__ float smem[4];   // 256 threads = 4 waves
    const int lane = threadIdx.x & 63;
    const int wave = threadIdx.x >> 6;
    if (lane == 0) smem[wave] = acc;
    __syncthreads();

    if (threadIdx.x == 0) {
        float s = smem[0] + smem[1] + smem[2] + smem[3];
        atomicAdd(out, s);   // device-scope by default on gfx950
    }
}

extern "C" void kernel_launch(void* const* d_in, const int* in_sizes, int n_in,
                              void* d_out, int out_size, void* d_ws, size_t ws_size,
                              hipStream_t stream) {
    const float* pred = (const float*)d_in[0];   // N+1 floats
    const float* x    = (const float*)d_in[1];   // N floats
    const float* y    = (const float*)d_in[2];   // N floats
    float* out = (float*)d_out;

    const int n  = in_sizes[1];
    const int n4 = n >> 2;

    TrajLoss_zero_kernel<<<1, 64, 0, stream>>>(out);

    const int block = 256;
    // 4096 blocks * 256 threads: each thread does exactly one unrolled
    // 4-float4 main iteration at N=16.7M (4096*256*16 = 16,777,216).
    const int grid = 4096;
    TrajLoss_6141803233879_kernel<<<grid, block, 0, stream>>>(pred, x, y, out, n4, n);
}